// Round 2
// baseline (108.523 us; speedup 1.0000x reference)
//
#include <hip/hip_runtime.h>
#include <math.h>

#define NQ 10
#define BATCHN 8192
#define PI_F 3.14159265358979f

// ---------------------------------------------------------------------------
// ws layout: [0..255]   int   per-wave flags (written unconditionally, no init)
//            [256..335] float gate coeffs G[p][8], p = bit position 0..9
//            [336..337] float (cos 2theta_f, sin 2theta_f) for final Ry
// ---------------------------------------------------------------------------

// Prep: per-wave any(in > 1) flags + gate-coefficient precompute.
// Launch with exactly 64 blocks x 256 threads (256 wave-flag slots).
__global__ __launch_bounds__(256) void prep_kernel(const float* __restrict__ in,
                                                   int n,
                                                   const float* __restrict__ w,
                                                   int* __restrict__ flags,
                                                   float* __restrict__ gates) {
    const int tid = blockIdx.x * 256 + threadIdx.x;
    bool pred = false;
    for (int i = tid; i < n; i += 64 * 256) pred |= (in[i] > 1.0f);
    const bool wany = __any(pred);
    const int wslot = (blockIdx.x << 2) | (threadIdx.x >> 6);
    if ((threadIdx.x & 63) == 0) flags[wslot] = wany ? 1 : 0;

    if (blockIdx.x == 0) {
        const int t = threadIdx.x;
        if (t < 80) {
            const int p = t >> 3;       // bit position
            const int j = t & 7;        // coeff index
            // bit p <-> qubit q = 9-p: Rx angle pi*w[12-p], Rz angle pi*w[22-p]
            float sx, cx, sz, cz;
            __sincosf(PI_F * w[12 - p], &sx, &cx);
            __sincosf(PI_F * w[22 - p], &sz, &cz);
            // g00=(cx*cz,-cx*sz) g01=(sx*sz,-sx*cz) g10=(-sx*sz,-sx*cz) g11=(cx*cz,cx*sz)
            float val;
            switch (j) {
                case 0: val =  cx * cz; break;
                case 1: val = -cx * sz; break;
                case 2: val =  sx * sz; break;
                case 3: val = -sx * cz; break;
                case 4: val = -sx * sz; break;
                case 5: val = -sx * cz; break;
                case 6: val =  cx * cz; break;
                default: val =  cx * sz; break;
            }
            gates[t] = val;
        } else if (t == 80) {
            float s2, c2;
            __sincosf(2.0f * PI_F * (w[0] + w[1] + w[2]), &s2, &c2);
            gates[80] = c2;
            gates[81] = s2;
        }
    }
}

// Register-local 2x2 butterfly on reg bit (mask m), coeffs from uniform ptr Gp.
#define REG_GATE(Gp, m)                                                        \
    {                                                                          \
        const float g00r = (Gp)[0], g00i = (Gp)[1], g01r = (Gp)[2],            \
                    g01i = (Gp)[3], g10r = (Gp)[4], g10i = (Gp)[5],            \
                    g11r = (Gp)[6], g11i = (Gp)[7];                            \
        _Pragma("unroll") for (int r = 0; r < 16; ++r) if (!(r & (m))) {       \
            const int r2 = r | (m);                                            \
            const float ar = re[r], ai = im[r];                                \
            const float br = re[r2], bi = im[r2];                              \
            re[r]  = g00r * ar - g00i * ai + g01r * br - g01i * bi;            \
            im[r]  = g00r * ai + g00i * ar + g01r * bi + g01i * br;            \
            re[r2] = g10r * ar - g10i * ai + g11r * br - g11i * bi;            \
            im[r2] = g10r * ai + g10i * ar + g11r * bi + g11i * br;            \
        }                                                                      \
    }

// Swap reg bit a with lane bit (shfl mask mb): 16 shuffles + 48 selects.
#define SWAP_STEP(a, mb)                                                       \
    {                                                                          \
        const bool hb = (lane & (mb)) != 0;                                    \
        _Pragma("unroll") for (int r0 = 0; r0 < 16; ++r0)                      \
            if (!(r0 & (1 << (a)))) {                                          \
                const int r1 = r0 | (1 << (a));                                \
                const float s_re = hb ? re[r0] : re[r1];                       \
                const float s_im = hb ? im[r0] : im[r1];                       \
                const float t_re = __shfl_xor(s_re, (mb), 64);                 \
                const float t_im = __shfl_xor(s_im, (mb), 64);                 \
                re[r0] = hb ? t_re : re[r0];                                   \
                im[r0] = hb ? t_im : im[r0];                                   \
                re[r1] = hb ? re[r1] : t_re;                                   \
                im[r1] = hb ? im[r1] : t_im;                                   \
            }                                                                  \
    }

// ---------------------------------------------------------------------------
// Main kernel. One wave per batch element, 16 complex amps/lane.
// Initial mapping: reg bits 0..3 = k4..k7; lane l0..3 = k0..3; l4=k8; l5=k9.
// Amp(k) = 2^-5 exp(i*pi*(S + (S^2-Q)/2)) at j = gray(k) (first E folded in).
// Gate sequence: reg gates k4..7 -> transpose A (reg<->l0..3) -> reg gates
// k0..3 -> transpose B (reg0,1<->l4,l5) -> reg gates k8,k9.
// Final layout: reg0=k8, reg1=k9 -> (t, t^768) pairing is reg-local (r^3),
// measurement sign = k9 = reg bit 1. Second E folded in throughout.
// ---------------------------------------------------------------------------
__global__ __launch_bounds__(256) void qsim_kernel(const float* __restrict__ in,
                                                   const int* __restrict__ flags,
                                                   const float* __restrict__ G,
                                                   float* __restrict__ out) {
    const int lane = threadIdx.x & 63;
    const int wid  = threadIdx.x >> 6;
    const int b    = blockIdx.x * 4 + wid;

    // ---- global any(in>1) flag: 256 wave-flags, one int4 per lane ----
    const int4 fv = ((const int4*)flags)[lane];
    const bool anyflag = __any((fv.x | fv.y | fv.z | fv.w) != 0);

    // ---- load 10 inputs, optional atan, broadcast ----
    float xv = 0.0f;
    if (lane < NQ) xv = in[b * NQ + lane];
    if (anyflag) xv = atanf(xv);
    float x[NQ];
#pragma unroll
    for (int q = 0; q < NQ; ++q) x[q] = __shfl(xv, q, 64);

    float Qs = 0.0f;
#pragma unroll
    for (int q = 0; q < NQ; ++q) Qs += x[q] * x[q];

    // ---- init amps.  j = gray(k): j_i = k_i ^ k_{i+1}; j_i -> x[9-i] ----
    // lane-only j bits: j0,j1,j2 (from k0..3 = lane low 4), j8 = l4^l5, j9 = l5
    const int jlo = (lane ^ (lane >> 1)) & 7;
    const int j8  = ((lane >> 4) ^ (lane >> 5)) & 1;
    const int j9  = (lane >> 5) & 1;
    float Sh = (jlo & 1 ? x[9] : -x[9]) + (jlo & 2 ? x[8] : -x[8]) +
               (jlo & 4 ? x[7] : -x[7]) + (j8 ? x[1] : -x[1]) +
               (j9 ? x[0] : -x[0]);
    const int k3 = (lane >> 3) & 1;
    const int k8 = (lane >> 4) & 1;

    float re[16], im[16];
#pragma unroll
    for (int r = 0; r < 16; ++r) {
        // r holds k4..7: j3 = k3^r0 -> x6; j4,j5,j6 = gray(r) bits -> x5,x4,x3;
        // j7 = r3^k8 -> x2
        const int gr = r ^ (r >> 1);
        const int j3 = k3 ^ (r & 1);
        const int j7 = ((r >> 3) & 1) ^ k8;
        const float S = Sh + (j3 ? x[6] : -x[6]) + (gr & 1 ? x[5] : -x[5]) +
                        (gr & 2 ? x[4] : -x[4]) + (gr & 4 ? x[3] : -x[3]) +
                        (j7 ? x[2] : -x[2]);
        const float th = PI_F * S + 0.5f * PI_F * (S * S - Qs);
        float sn, cs;
        __sincosf(th, &sn, &cs);
        re[r] = 0.03125f * cs;
        im[r] = 0.03125f * sn;
    }

    // ---- gates on k4..k7 (reg bits 0..3) ----
    REG_GATE(G + 8 * 4, 1)
    REG_GATE(G + 8 * 5, 2)
    REG_GATE(G + 8 * 6, 4)
    REG_GATE(G + 8 * 7, 8)

    // ---- transpose A: reg bit a <-> lane bit a (k4..7 <-> k0..3) ----
    SWAP_STEP(0, 1)
    SWAP_STEP(1, 2)
    SWAP_STEP(2, 4)
    SWAP_STEP(3, 8)

    // ---- gates on k0..k3 (now reg bits 0..3) ----
    REG_GATE(G + 8 * 0, 1)
    REG_GATE(G + 8 * 1, 2)
    REG_GATE(G + 8 * 2, 4)
    REG_GATE(G + 8 * 3, 8)

    // ---- transpose B: reg0 <-> l4 (k8), reg1 <-> l5 (k9) ----
    SWAP_STEP(0, 16)
    SWAP_STEP(1, 32)

    // ---- gates on k8 (reg bit 0), k9 (reg bit 1) ----
    REG_GATE(G + 8 * 8, 1)
    REG_GATE(G + 8 * 9, 2)

    // ---- final Ry through second E: pair (r, r^3), sign = k9 = reg bit 1.
    //      |B'|^2 - |A'|^2 = c2*(pb - pa) + 2*s2*dot ----
    const float c2   = G[80];
    const float s2x2 = 2.0f * G[81];
    float acc = 0.0f;
#pragma unroll
    for (int r = 0; r < 16; ++r) {
        if (!(r & 2)) {  // k9 = 0 element of the pair
            const int rp = r ^ 3;
            const float pa  = re[r] * re[r] + im[r] * im[r];
            const float pb  = re[rp] * re[rp] + im[rp] * im[rp];
            const float dot = re[r] * re[rp] + im[r] * im[rp];
            acc += c2 * (pb - pa) + s2x2 * dot;
        }
    }

    // ---- wave reduction ----
#pragma unroll
    for (int m = 1; m < 64; m <<= 1) acc += __shfl_xor(acc, m, 64);
    if (lane == 0) out[b] = acc;
}

extern "C" void kernel_launch(void* const* d_in, const int* in_sizes, int n_in,
                              void* d_out, int out_size, void* d_ws, size_t ws_size,
                              hipStream_t stream) {
    const float* inputs = (const float*)d_in[0];   // (8192, 10) float32
    const float* weight = (const float*)d_in[1];   // (23,) float32
    // d_in[2] = entangle_matrix — analytically folded (Gray-code map), unused.
    float* out  = (float*)d_out;                   // (8192,) float32
    int* flags  = (int*)d_ws;                      // 256 ints
    float* gates = (float*)d_ws + 256;             // 82 floats

    prep_kernel<<<64, 256, 0, stream>>>(inputs, BATCHN * NQ, weight, flags, gates);
    qsim_kernel<<<BATCHN / 4, 256, 0, stream>>>(inputs, flags, gates, out);
}

// Round 3
// 82.832 us; speedup vs baseline: 1.3102x; 1.3102x over previous
//
#include <hip/hip_runtime.h>
#include <math.h>

#define NQ 10
#define BATCHN 8192
#define PI_F 3.14159265358979f

// ---------------------------------------------------------------------------
// ws layout: [0..63]  int   per-block any(in>1) flags (written unconditionally)
//            [64..95] float gate table:
//              gtab[2p]   = cos(pi*w[12-p])   (Rx coeff, bit p = qubit 9-p)
//              gtab[2p+1] = sin(pi*w[12-p])
//              gtab[20]   = cos(2pi*(w0+w1+w2)),  gtab[21] = sin(...)
//              gtab[22+p] = w[22-p]            (Rz angle/2pi for bit p)
// ---------------------------------------------------------------------------
__global__ __launch_bounds__(256) void prep_kernel(const float* __restrict__ in,
                                                   int n,
                                                   const float* __restrict__ w,
                                                   int* __restrict__ flags,
                                                   float* __restrict__ gtab) {
    __shared__ int bf;
    if (threadIdx.x == 0) bf = 0;
    __syncthreads();
    const int tid = blockIdx.x * 256 + threadIdx.x;
    bool pred = false;
    for (int i = tid; i < n; i += 64 * 256) pred |= (in[i] > 1.0f);
    if (__any(pred) && (threadIdx.x & 63) == 0) atomicOr(&bf, 1);
    __syncthreads();
    if (threadIdx.x == 0) flags[blockIdx.x] = bf;

    if (blockIdx.x == 0) {
        const int t = threadIdx.x;
        if (t < 10) {
            float s, c;
            __sincosf(PI_F * w[12 - t], &s, &c);
            gtab[2 * t]     = c;
            gtab[2 * t + 1] = s;
            gtab[22 + t]    = w[22 - t];
        } else if (t == 10) {
            float s2, c2;
            __sincosf(2.0f * PI_F * (w[0] + w[1] + w[2]), &s2, &c2);
            gtab[20] = c2;
            gtab[21] = s2;
        }
    }
}

// force a wave-uniform float into an SGPR
__device__ __forceinline__ float rfl(float v) {
    return __uint_as_float(__builtin_amdgcn_readfirstlane(__float_as_uint(v)));
}

// Rx butterfly on register bit m (coeffs c,s wave-uniform)
#define GATE_REG(c, s, m)                                                      \
    {                                                                          \
        _Pragma("unroll") for (int r = 0; r < 16; ++r) if (!(r & (m))) {       \
            const int r2 = r | (m);                                            \
            const float ar = re[r], ai = im[r];                                \
            const float br = re[r2], bi = im[r2];                              \
            re[r]  = fmaf((c), ar,  (s) * bi);                                 \
            im[r]  = fmaf((c), ai, -(s) * br);                                 \
            re[r2] = fmaf((c), br,  (s) * ai);                                 \
            im[r2] = fmaf((c), bi, -(s) * ar);                                 \
        }                                                                      \
    }

// Rx butterfly on lane bit mb: side-symmetric, no selects needed
#define GATE_LANE(c, s, mb)                                                    \
    {                                                                          \
        _Pragma("unroll") for (int r = 0; r < 16; ++r) {                       \
            const float pr  = __shfl_xor(re[r], (mb), 64);                     \
            const float pim = __shfl_xor(im[r], (mb), 64);                     \
            re[r] = fmaf((c), re[r],  (s) * pim);                              \
            im[r] = fmaf((c), im[r], -(s) * pr);                               \
        }                                                                      \
    }

// ---------------------------------------------------------------------------
// One wave per batch element, 16 complex amps/lane.
// k bits: lane l0..3 = k0..k3, l4 = k8, l5 = k9; reg bits 0..3 = k4..k7.
// Init phase (revolutions): 0.25*T^2 - 0.25*(1+Q) + 0.5*W, T = S+1,
//   S over j = gray(k) (first E folded), W = Rz fold over bits of k.
// Gates: pure Rx butterflies (Rz folded into init).
// Final Ry through second E: partner = lane^48 (flips k8,k9), sign = k9.
// ---------------------------------------------------------------------------
__global__ __launch_bounds__(256, 4) void qsim_kernel(const float* __restrict__ in,
                                                      const int* __restrict__ flags,
                                                      const float* __restrict__ G,
                                                      float* __restrict__ out) {
    const int lane = threadIdx.x & 63;
    const int b    = blockIdx.x * 4 + (threadIdx.x >> 6);

    // global any-flag: 64 ints, one dword per lane (256B footprint)
    const bool anyflag = __any(flags[lane] != 0);

    // load 10 inputs, optional atan, broadcast to SGPR-resident x[]
    float xv = 0.0f;
    if (lane < NQ) xv = in[b * NQ + lane];
    if (anyflag) xv = atanf(xv);
    float x[NQ];
#pragma unroll
    for (int q = 0; q < NQ; ++q) x[q] = rfl(__shfl(xv, q, 64));

    float Qs = 0.0f;
#pragma unroll
    for (int q = 0; q < NQ; ++q) Qs += x[q] * x[q];

    // gate table -> SGPRs
    float gc[NQ], gs[NQ], wz[NQ];
#pragma unroll
    for (int p = 0; p < NQ; ++p) {
        gc[p] = rfl(G[2 * p]);
        gs[p] = rfl(G[2 * p + 1]);
        wz[p] = rfl(G[22 + p]);
    }
    const float c2 = rfl(G[20]);
    const float s2 = rfl(G[21]);

    // ---- init phases ----
    const int jlo = (lane ^ (lane >> 1)) & 7;       // j0,j1,j2
    const int j8  = ((lane >> 4) ^ (lane >> 5)) & 1;
    const int k9  = (lane >> 5) & 1;                // = j9
    const int k3  = (lane >> 3) & 1;
    const int k8  = (lane >> 4) & 1;

    const float Sh1 = 1.0f
        + (jlo & 1 ? x[9] : -x[9])
        + (jlo & 2 ? x[8] : -x[8])
        + (jlo & 4 ? x[7] : -x[7])
        + (j8 ? x[1] : -x[1])
        + (k9 ? x[0] : -x[0]);
    const float x6s = k3 ? x[6] : -x[6];            // j3 = k3 ^ r0
    const float x2s = k8 ? x[2] : -x[2];            // j7 = r3 ^ k8

    const float Dl = 0.5f * (
          ((lane & 1) ? wz[0] : -wz[0])
        + ((lane & 2) ? wz[1] : -wz[1])
        + ((lane & 4) ? wz[2] : -wz[2])
        + ((lane & 8) ? wz[3] : -wz[3])
        + (k8 ? wz[8] : -wz[8])
        + (k9 ? wz[9] : -wz[9]))
        - 0.25f * (1.0f + Qs);
    const float h4 = 0.5f * wz[4], h5 = 0.5f * wz[5];
    const float h6 = 0.5f * wz[6], h7 = 0.5f * wz[7];

    float re[16], im[16];
#pragma unroll
    for (int r = 0; r < 16; ++r) {
        const int gr = r ^ (r >> 1);
        const float T = Sh1
            + ((r & 1) ? -x6s : x6s)
            + (gr & 1 ? x[5] : -x[5])
            + (gr & 2 ? x[4] : -x[4])
            + (gr & 4 ? x[3] : -x[3])
            + ((r & 8) ? -x2s : x2s);
        const float D = Dl
            + ((r & 1) ? h4 : -h4)
            + ((r & 2) ? h5 : -h5)
            + ((r & 4) ? h6 : -h6)
            + ((r & 8) ? h7 : -h7);
        const float rev = fmaf(0.25f * T, T, D);    // phase in revolutions
        im[r] = __builtin_amdgcn_sinf(rev);         // v_sin_f32 (input: revs)
        re[r] = __builtin_amdgcn_cosf(rev);
    }

    // ---- 10 Rx gates ----
    GATE_REG(gc[4], gs[4], 1)       // k4
    GATE_REG(gc[5], gs[5], 2)       // k5
    GATE_REG(gc[6], gs[6], 4)       // k6
    GATE_REG(gc[7], gs[7], 8)       // k7
    GATE_LANE(gc[0], gs[0], 1)      // k0
    GATE_LANE(gc[1], gs[1], 2)      // k1
    GATE_LANE(gc[2], gs[2], 4)      // k2
    GATE_LANE(gc[3], gs[3], 8)      // k3
    GATE_LANE(gc[8], gs[8], 16)     // k8
    GATE_LANE(gc[9], gs[9], 32)     // k9

    // ---- final Ry through second E: partner = lane^48, sign = k9 ----
    const float cc = k9 ? c2 : -c2;
    float acc = 0.0f;
#pragma unroll
    for (int r = 0; r < 16; ++r) {
        const float pr  = __shfl_xor(re[r], 48, 64);
        const float pim = __shfl_xor(im[r], 48, 64);
        const float pown = fmaf(re[r], re[r], im[r] * im[r]);
        const float dot  = fmaf(re[r], pr, im[r] * pim);
        acc = fmaf(cc, pown, acc);
        acc = fmaf(s2, dot, acc);
    }

    // ---- wave reduction + 2^-10 normalization ----
#pragma unroll
    for (int m = 1; m < 64; m <<= 1) acc += __shfl_xor(acc, m, 64);
    if (lane == 0) out[b] = acc * 0.0009765625f;
}

extern "C" void kernel_launch(void* const* d_in, const int* in_sizes, int n_in,
                              void* d_out, int out_size, void* d_ws, size_t ws_size,
                              hipStream_t stream) {
    const float* inputs = (const float*)d_in[0];   // (8192, 10) float32
    const float* weight = (const float*)d_in[1];   // (23,) float32
    // d_in[2] = entangle_matrix — analytically folded (Gray-code map), unused.
    float* out   = (float*)d_out;                  // (8192,) float32
    int*   flags = (int*)d_ws;                     // 64 ints
    float* gtab  = (float*)d_ws + 64;              // 32 floats

    prep_kernel<<<64, 256, 0, stream>>>(inputs, BATCHN * NQ, weight, flags, gtab);
    qsim_kernel<<<BATCHN / 4, 256, 0, stream>>>(inputs, flags, gtab, out);
}

// Round 4
// 77.701 us; speedup vs baseline: 1.3967x; 1.0660x over previous
//
#include <hip/hip_runtime.h>
#include <math.h>

#define NQ 10
#define BATCHN 8192
#define PI_F 3.14159265358979f

// ---------------------------------------------------------------------------
// ws layout: [0..63]  int   per-block any(in>1) flags (written unconditionally)
//            [64..95] float gate table:
//              gtab[2p]   = cos(pi*w[12-p])   (Rx coeff, bit p = qubit 9-p)
//              gtab[2p+1] = sin(pi*w[12-p])
//              gtab[20]   = cos(2pi*(w0+w1+w2)),  gtab[21] = sin(...)
//              gtab[22+p] = w[22-p]            (Rz angle/2pi for bit p)
// ---------------------------------------------------------------------------
__global__ __launch_bounds__(256) void prep_kernel(const float* __restrict__ in,
                                                   int n,
                                                   const float* __restrict__ w,
                                                   int* __restrict__ flags,
                                                   float* __restrict__ gtab) {
    __shared__ int bf;
    if (threadIdx.x == 0) bf = 0;
    __syncthreads();
    const int tid = blockIdx.x * 256 + threadIdx.x;
    bool pred = false;
    for (int i = tid; i < n; i += 64 * 256) pred |= (in[i] > 1.0f);
    if (__any(pred) && (threadIdx.x & 63) == 0) atomicOr(&bf, 1);
    __syncthreads();
    if (threadIdx.x == 0) flags[blockIdx.x] = bf;

    if (blockIdx.x == 0) {
        const int t = threadIdx.x;
        if (t < 10) {
            float s, c;
            __sincosf(PI_F * w[12 - t], &s, &c);
            gtab[2 * t]     = c;
            gtab[2 * t + 1] = s;
            gtab[22 + t]    = w[22 - t];
        } else if (t == 10) {
            float s2, c2;
            __sincosf(2.0f * PI_F * (w[0] + w[1] + w[2]), &s2, &c2);
            gtab[20] = c2;
            gtab[21] = s2;
        }
    }
}

__device__ __forceinline__ float rfl(float v) {
    return __uint_as_float(__builtin_amdgcn_readfirstlane(__float_as_uint(v)));
}
__device__ __forceinline__ float rdlane(float v, int l) {
    return __uint_as_float(__builtin_amdgcn_readlane(__float_as_uint(v), l));
}
// lane-crossing ops that stay OFF the DS pipe where possible
__device__ __forceinline__ float xor1_dpp(float v) {   // quad_perm [1,0,3,2]
    return __int_as_float(__builtin_amdgcn_update_dpp(
        __float_as_int(v), __float_as_int(v), 0xB1, 0xF, 0xF, true));
}
__device__ __forceinline__ float xor2_dpp(float v) {   // quad_perm [2,3,0,1]
    return __int_as_float(__builtin_amdgcn_update_dpp(
        __float_as_int(v), __float_as_int(v), 0x4E, 0xF, 0xF, true));
}
__device__ __forceinline__ float xor4_swz(float v) {   // ds_swizzle xor-4
    return __int_as_float(__builtin_amdgcn_ds_swizzle(__float_as_int(v), 0x101F));
}
__device__ __forceinline__ float xor8_swz(float v) {   // ds_swizzle xor-8
    return __int_as_float(__builtin_amdgcn_ds_swizzle(__float_as_int(v), 0x201F));
}

#define HAVE_PLSWAP (__has_builtin(__builtin_amdgcn_permlane16_swap))
#if HAVE_PLSWAP
typedef unsigned uv2 __attribute__((ext_vector_type(2)));
__device__ __forceinline__ void pl16_swap(float& a, float& b) {
    uv2 r = __builtin_amdgcn_permlane16_swap(__float_as_uint(a),
                                             __float_as_uint(b), false, false);
    a = __uint_as_float(r.x);
    b = __uint_as_float(r.y);
}
__device__ __forceinline__ void pl32_swap(float& a, float& b) {
    uv2 r = __builtin_amdgcn_permlane32_swap(__float_as_uint(a),
                                             __float_as_uint(b), false, false);
    a = __uint_as_float(r.x);
    b = __uint_as_float(r.y);
}
#endif

// Rx butterfly on register bit m
#define GATE_REG(c, s, m)                                                      \
    {                                                                          \
        _Pragma("unroll") for (int r = 0; r < 16; ++r) if (!(r & (m))) {       \
            const int r2 = r | (m);                                            \
            const float ar = re[r], ai = im[r];                                \
            const float br = re[r2], bi = im[r2];                              \
            re[r]  = fmaf((c), ar,  (s) * bi);                                 \
            im[r]  = fmaf((c), ai, -(s) * br);                                 \
            re[r2] = fmaf((c), br,  (s) * ai);                                 \
            im[r2] = fmaf((c), bi, -(s) * ar);                                 \
        }                                                                      \
    }

// Rx butterfly on a lane bit via exchange functor EXCH (side-symmetric)
#define GATE_LANE_EX(c, s, EXCH)                                               \
    {                                                                          \
        _Pragma("unroll") for (int r = 0; r < 16; ++r) {                       \
            const float pr  = EXCH(re[r]);                                     \
            const float pim = EXCH(im[r]);                                     \
            re[r] = fmaf((c), re[r],  (s) * pim);                              \
            im[r] = fmaf((c), im[r], -(s) * pr);                               \
        }                                                                      \
    }

// ---------------------------------------------------------------------------
// One wave per batch element, 16 complex amps/lane.
// k bits: lane l0..3 = k0..k3, l4 = k8, l5 = k9; reg bits 0..3 = k4..k7.
// Init phase (revolutions): 0.25*T^2 - 0.25*(1+Q) + 0.5*W, T = S+1,
//   S over j = gray(k) (first E folded), W = Rz fold over bits of k.
// Gates: pure Rx butterflies (Rz folded into init).
//   k4..k7: reg gates.  k0,k1: DPP quad_perm.  k2,k3: ds_swizzle.
//   k8,k9: permlane16/32_swap transposes -> reg gates -> final pairing
//   (t, t^768) is register-local (r ^ 3), sign = k9 = reg bit 1.
// ---------------------------------------------------------------------------
__global__ __launch_bounds__(256, 4) void qsim_kernel(const float* __restrict__ in,
                                                      const int* __restrict__ flags,
                                                      const float* __restrict__ G,
                                                      float* __restrict__ out) {
    const int lane = threadIdx.x & 63;
    const int b    = blockIdx.x * 4 + (threadIdx.x >> 6);

    const bool anyflag = __any(flags[lane] != 0);

    float xv = 0.0f;
    if (lane < NQ) xv = in[b * NQ + lane];
    if (anyflag) xv = atanf(xv);
    float x[NQ];
#pragma unroll
    for (int q = 0; q < NQ; ++q) x[q] = rdlane(xv, q);

    float Qs = 0.0f;
#pragma unroll
    for (int q = 0; q < NQ; ++q) Qs += x[q] * x[q];

    float gc[NQ], gs[NQ], wz[NQ];
#pragma unroll
    for (int p = 0; p < NQ; ++p) {
        gc[p] = rfl(G[2 * p]);
        gs[p] = rfl(G[2 * p + 1]);
        wz[p] = rfl(G[22 + p]);
    }
    const float c2 = rfl(G[20]);
    const float s2 = rfl(G[21]);

    // ---- init phases ----
    const int jlo = (lane ^ (lane >> 1)) & 7;
    const int j8  = ((lane >> 4) ^ (lane >> 5)) & 1;
    const int k9  = (lane >> 5) & 1;
    const int k3  = (lane >> 3) & 1;
    const int k8  = (lane >> 4) & 1;

    const float Sh1 = 1.0f
        + (jlo & 1 ? x[9] : -x[9])
        + (jlo & 2 ? x[8] : -x[8])
        + (jlo & 4 ? x[7] : -x[7])
        + (j8 ? x[1] : -x[1])
        + (k9 ? x[0] : -x[0]);
    const float x6s = k3 ? x[6] : -x[6];
    const float x2s = k8 ? x[2] : -x[2];

    const float Dl = 0.5f * (
          ((lane & 1) ? wz[0] : -wz[0])
        + ((lane & 2) ? wz[1] : -wz[1])
        + ((lane & 4) ? wz[2] : -wz[2])
        + ((lane & 8) ? wz[3] : -wz[3])
        + (k8 ? wz[8] : -wz[8])
        + (k9 ? wz[9] : -wz[9]))
        - 0.25f * (1.0f + Qs);
    const float h4 = 0.5f * wz[4], h5 = 0.5f * wz[5];
    const float h6 = 0.5f * wz[6], h7 = 0.5f * wz[7];

    float re[16], im[16];
#pragma unroll
    for (int r = 0; r < 16; ++r) {
        const int gr = r ^ (r >> 1);
        const float T = Sh1
            + ((r & 1) ? -x6s : x6s)
            + (gr & 1 ? x[5] : -x[5])
            + (gr & 2 ? x[4] : -x[4])
            + (gr & 4 ? x[3] : -x[3])
            + ((r & 8) ? -x2s : x2s);
        const float D = Dl
            + ((r & 1) ? h4 : -h4)
            + ((r & 2) ? h5 : -h5)
            + ((r & 4) ? h6 : -h6)
            + ((r & 8) ? h7 : -h7);
        const float rev = fmaf(0.25f * T, T, D);
        im[r] = __builtin_amdgcn_sinf(rev);
        re[r] = __builtin_amdgcn_cosf(rev);
    }

    // ---- gates ----
    GATE_REG(gc[4], gs[4], 1)            // k4 (reg bit 0)
    GATE_REG(gc[5], gs[5], 2)            // k5
    GATE_REG(gc[6], gs[6], 4)            // k6
    GATE_REG(gc[7], gs[7], 8)            // k7
    GATE_LANE_EX(gc[0], gs[0], xor1_dpp) // k0 (lane bit 0, VALU)
    GATE_LANE_EX(gc[1], gs[1], xor2_dpp) // k1 (VALU)
    GATE_LANE_EX(gc[2], gs[2], xor4_swz) // k2 (DS swizzle)
    GATE_LANE_EX(gc[3], gs[3], xor8_swz) // k3 (DS swizzle)

    float acc = 0.0f;
#if HAVE_PLSWAP
    // transpose reg bit 0 <-> lane bit 4 (k4 <-> k8): one VALU op per pair
#pragma unroll
    for (int r = 0; r < 16; r += 2) {
        pl16_swap(re[r], re[r + 1]);
        pl16_swap(im[r], im[r + 1]);
    }
    GATE_REG(gc[8], gs[8], 1)            // k8 (now reg bit 0)
    // transpose reg bit 1 <-> lane bit 5 (k5 <-> k9)
#pragma unroll
    for (int r = 0; r < 16; ++r) {
        if (!(r & 2)) {
            pl32_swap(re[r], re[r | 2]);
            pl32_swap(im[r], im[r | 2]);
        }
    }
    GATE_REG(gc[9], gs[9], 2)            // k9 (now reg bit 1)

    // final Ry through second E: pair (r, r^3) flips k8,k9; sign = reg bit 1
    const float s2x2 = 2.0f * s2;
#pragma unroll
    for (int r = 0; r < 16; ++r) {
        if (!(r & 2)) {
            const int rp = r ^ 3;
            const float pa  = fmaf(re[r],  re[r],  im[r]  * im[r]);
            const float pb  = fmaf(re[rp], re[rp], im[rp] * im[rp]);
            const float dot = fmaf(re[r],  re[rp], im[r]  * im[rp]);
            acc += c2 * (pb - pa) + s2x2 * dot;
        }
    }
#else
    // fallback: shuffle butterflies for k8,k9 + lane-pair finale
    GATE_LANE_EX(gc[8], gs[8], [&](float v) { return __shfl_xor(v, 16, 64); })
    GATE_LANE_EX(gc[9], gs[9], [&](float v) { return __shfl_xor(v, 32, 64); })
    const float cc = k9 ? c2 : -c2;
#pragma unroll
    for (int r = 0; r < 16; ++r) {
        const float pr  = __shfl_xor(re[r], 48, 64);
        const float pim = __shfl_xor(im[r], 48, 64);
        const float pown = fmaf(re[r], re[r], im[r] * im[r]);
        const float dot  = fmaf(re[r], pr, im[r] * pim);
        acc = fmaf(cc, pown, acc);
        acc = fmaf(s2, dot, acc);
    }
#endif

    // ---- wave reduction: DPP for 1,2; swizzle 4,8; shfl 16,32 ----
    acc += xor1_dpp(acc);
    acc += xor2_dpp(acc);
    acc += xor4_swz(acc);
    acc += xor8_swz(acc);
    acc += __shfl_xor(acc, 16, 64);
    acc += __shfl_xor(acc, 32, 64);
    if (lane == 0) out[b] = acc * 0.0009765625f;
}

extern "C" void kernel_launch(void* const* d_in, const int* in_sizes, int n_in,
                              void* d_out, int out_size, void* d_ws, size_t ws_size,
                              hipStream_t stream) {
    const float* inputs = (const float*)d_in[0];   // (8192, 10) float32
    const float* weight = (const float*)d_in[1];   // (23,) float32
    // d_in[2] = entangle_matrix — analytically folded (Gray-code map), unused.
    float* out   = (float*)d_out;                  // (8192,) float32
    int*   flags = (int*)d_ws;                     // 64 ints
    float* gtab  = (float*)d_ws + 64;              // 32 floats

    prep_kernel<<<64, 256, 0, stream>>>(inputs, BATCHN * NQ, weight, flags, gtab);
    qsim_kernel<<<BATCHN / 4, 256, 0, stream>>>(inputs, flags, gtab, out);
}

// Round 5
// 72.295 us; speedup vs baseline: 1.5011x; 1.0748x over previous
//
#include <hip/hip_runtime.h>
#include <math.h>

#define NQ 10
#define BATCHN 8192
#define PI_F 3.14159265358979f

typedef float v2f __attribute__((ext_vector_type(2)));

// ---------------------------------------------------------------------------
// ws layout: [0..63]  int   per-block any(in>1) flags (written unconditionally)
//            [64..95] float gate table (see prep_kernel)
// ---------------------------------------------------------------------------
__global__ __launch_bounds__(256) void prep_kernel(const float* __restrict__ in,
                                                   int n,
                                                   const float* __restrict__ w,
                                                   int* __restrict__ flags,
                                                   float* __restrict__ gtab) {
    __shared__ int bf;
    if (threadIdx.x == 0) bf = 0;
    __syncthreads();
    const int tid = blockIdx.x * 256 + threadIdx.x;
    bool pred = false;
    for (int i = tid; i < n; i += 64 * 256) pred |= (in[i] > 1.0f);
    if (__any(pred) && (threadIdx.x & 63) == 0) atomicOr(&bf, 1);
    __syncthreads();
    if (threadIdx.x == 0) flags[blockIdx.x] = bf;

    if (blockIdx.x == 0) {
        const int t = threadIdx.x;
        if (t < 10) {
            float s, c;
            __sincosf(PI_F * w[12 - t], &s, &c);
            gtab[2 * t]     = c;        // Rx cos for bit p = t (qubit 9-p)
            gtab[2 * t + 1] = s;        // Rx sin
            gtab[22 + t]    = w[22 - t];// Rz angle/2pi
        } else if (t == 10) {
            float s2, c2;
            __sincosf(2.0f * PI_F * (w[0] + w[1] + w[2]), &s2, &c2);
            gtab[20] = c2;
            gtab[21] = s2;
        }
    }
}

__device__ __forceinline__ float rfl(float v) {
    return __uint_as_float(__builtin_amdgcn_readfirstlane(__float_as_uint(v)));
}
__device__ __forceinline__ float rdlane(float v, int l) {
    return __uint_as_float(__builtin_amdgcn_readlane(__float_as_uint(v), l));
}
__device__ __forceinline__ float xor1_dpp(float v) {   // quad_perm [1,0,3,2]
    return __int_as_float(__builtin_amdgcn_update_dpp(
        __float_as_int(v), __float_as_int(v), 0xB1, 0xF, 0xF, true));
}
__device__ __forceinline__ float xor2_dpp(float v) {   // quad_perm [2,3,0,1]
    return __int_as_float(__builtin_amdgcn_update_dpp(
        __float_as_int(v), __float_as_int(v), 0x4E, 0xF, 0xF, true));
}
__device__ __forceinline__ float xor4_swz(float v) {   // ds_swizzle xor-4
    return __int_as_float(__builtin_amdgcn_ds_swizzle(__float_as_int(v), 0x101F));
}
__device__ __forceinline__ float xor8_swz(float v) {   // ds_swizzle xor-8
    return __int_as_float(__builtin_amdgcn_ds_swizzle(__float_as_int(v), 0x201F));
}
__device__ __forceinline__ v2f vfma(v2f a, v2f b, v2f c) {
    return __builtin_elementwise_fma(a, b, c);
}
__device__ __forceinline__ v2f splat(float v) { return (v2f){v, v}; }
__device__ __forceinline__ v2f vswap(v2f v) {
    return __builtin_shufflevector(v, v, 1, 0);
}

#define HAVE_PLSWAP (__has_builtin(__builtin_amdgcn_permlane16_swap))
#if HAVE_PLSWAP
typedef unsigned uv2 __attribute__((ext_vector_type(2)));
__device__ __forceinline__ void pl16_swap(float& a, float& b) {
    uv2 r = __builtin_amdgcn_permlane16_swap(__float_as_uint(a),
                                             __float_as_uint(b), false, false);
    a = __uint_as_float(r.x);
    b = __uint_as_float(r.y);
}
__device__ __forceinline__ void pl32_swap(float& a, float& b) {
    uv2 r = __builtin_amdgcn_permlane32_swap(__float_as_uint(a),
                                             __float_as_uint(b), false, false);
    a = __uint_as_float(r.x);
    b = __uint_as_float(r.y);
}
#endif

// Packed Rx butterfly on reg bit m (m in {1,2,4}, indices 0..7)
#define GATE_REG2(c, s, m)                                                     \
    {                                                                          \
        const v2f cv = splat(c), sv = splat(s), nsv = splat(-(s));             \
        _Pragma("unroll") for (int r = 0; r < 8; ++r) if (!(r & (m))) {        \
            const int r2 = r | (m);                                            \
            const v2f ar = re2[r], ai = im2[r];                                \
            const v2f br = re2[r2], bi = im2[r2];                              \
            re2[r]  = vfma(cv, ar, sv * bi);                                   \
            im2[r]  = vfma(cv, ai, nsv * br);                                  \
            re2[r2] = vfma(cv, br, sv * ai);                                   \
            im2[r2] = vfma(cv, bi, nsv * ar);                                  \
        }                                                                      \
    }

// Packed Rx butterfly on a lane bit via scalar exchange functor EXCH
#define GATE_LANE2(c, s, EXCH)                                                 \
    {                                                                          \
        const v2f cv = splat(c), sv = splat(s), nsv = splat(-(s));             \
        _Pragma("unroll") for (int r = 0; r < 8; ++r) {                        \
            v2f pr, pim;                                                       \
            pr.x  = EXCH(re2[r].x);  pr.y  = EXCH(re2[r].y);                   \
            pim.x = EXCH(im2[r].x);  pim.y = EXCH(im2[r].y);                   \
            re2[r] = vfma(cv, re2[r], sv * pim);                               \
            im2[r] = vfma(cv, im2[r], nsv * pr);                               \
        }                                                                      \
    }

// ---------------------------------------------------------------------------
// One wave per batch element; 16 complex amps/lane packed as v2f[8].
// k bits: lane l0..3 = k0..k3, l4 = k8, l5 = k9; reg idx bits 0..2 = k4..k6;
// v2f component = k7.  Phases: 0.25*T^2 + D over j = gray(k) (first E folded,
// Rz layer folded into D).  Gates: pure Rx.  k7 = in-register component swap.
// k8,k9 via permlane16/32_swap transposes -> packed reg gates; final pairing
// (t, t^768) flips k8,k9 = reg-local r^3, sign = k9 = reg bit 1.
// ---------------------------------------------------------------------------
__global__ __launch_bounds__(256, 8) void qsim_kernel(const float* __restrict__ in,
                                                      const int* __restrict__ flags,
                                                      const float* __restrict__ G,
                                                      float* __restrict__ out) {
    const int lane = threadIdx.x & 63;
    const int b    = blockIdx.x * 4 + (threadIdx.x >> 6);

    const bool anyflag = __any(flags[lane] != 0);

    float xv = 0.0f;
    if (lane < NQ) xv = in[b * NQ + lane];
    if (anyflag) xv = atanf(xv);
    float x[NQ];
#pragma unroll
    for (int q = 0; q < NQ; ++q) x[q] = rdlane(xv, q);

    float Qs = 0.0f;
#pragma unroll
    for (int q = 0; q < NQ; ++q) Qs += x[q] * x[q];

    float gc[NQ], gs[NQ], wz[NQ];
#pragma unroll
    for (int p = 0; p < NQ; ++p) {
        gc[p] = rfl(G[2 * p]);
        gs[p] = rfl(G[2 * p + 1]);
        wz[p] = rfl(G[22 + p]);
    }
    const float c2 = rfl(G[20]);
    const float s2 = rfl(G[21]);

    // ---- init phases ----
    const int jlo = (lane ^ (lane >> 1)) & 7;
    const int j8  = ((lane >> 4) ^ (lane >> 5)) & 1;
    const int k9  = (lane >> 5) & 1;
    const int k3  = (lane >> 3) & 1;
    const int k8  = (lane >> 4) & 1;

    const float Sh1 = 1.0f
        + (jlo & 1 ? x[9] : -x[9])
        + (jlo & 2 ? x[8] : -x[8])
        + (jlo & 4 ? x[7] : -x[7])
        + (j8 ? x[1] : -x[1])
        + (k9 ? x[0] : -x[0]);
    const float x6s = k3 ? x[6] : -x[6];            // j3 = k3 ^ r0
    const float x2s = k8 ? x[2] : -x[2];            // j7 = k7 ^ k8

    const float Dl = 0.5f * (
          ((lane & 1) ? wz[0] : -wz[0])
        + ((lane & 2) ? wz[1] : -wz[1])
        + ((lane & 4) ? wz[2] : -wz[2])
        + ((lane & 8) ? wz[3] : -wz[3])
        + (k8 ? wz[8] : -wz[8])
        + (k9 ? wz[9] : -wz[9]))
        - 0.25f * (1.0f + Qs);
    const float h4 = 0.5f * wz[4], h5 = 0.5f * wz[5];
    const float h6 = 0.5f * wz[6], h7 = 0.5f * wz[7];

    v2f re2[8], im2[8];
#pragma unroll
    for (int r = 0; r < 8; ++r) {
        // scalar part common to both components (component = k7)
        const int g0 = (r ^ (r >> 1)) & 1;          // k4^k5
        const int g1 = ((r >> 1) ^ (r >> 2)) & 1;   // k5^k6
        const float Tc = Sh1
            + ((r & 1) ? -x6s : x6s)
            + (g0 ? x[5] : -x[5])
            + (g1 ? x[4] : -x[4]);
        const float v = ((r & 4) ? x[3] : -x[3]) + x2s;  // sign flips with k7
        const float Dc = Dl
            + ((r & 1) ? h4 : -h4)
            + ((r & 2) ? h5 : -h5)
            + ((r & 4) ? h6 : -h6);
        const v2f T2 = {Tc + v, Tc - v};
        const v2f D2 = {Dc - h7, Dc + h7};
        const v2f rev = vfma(splat(0.25f) * T2, T2, D2);
        im2[r] = (v2f){__builtin_amdgcn_sinf(rev.x), __builtin_amdgcn_sinf(rev.y)};
        re2[r] = (v2f){__builtin_amdgcn_cosf(rev.x), __builtin_amdgcn_cosf(rev.y)};
    }

    // ---- gates on k4,k5,k6 (reg bits 0..2, packed) ----
    GATE_REG2(gc[4], gs[4], 1)
    GATE_REG2(gc[5], gs[5], 2)
    GATE_REG2(gc[6], gs[6], 4)

    // ---- gate on k7: component swap within each v2f ----
    {
        const v2f cv = splat(gc[7]), sv = splat(gs[7]), nsv = splat(-gs[7]);
#pragma unroll
        for (int r = 0; r < 8; ++r) {
            const v2f pr = vswap(re2[r]), pim = vswap(im2[r]);
            re2[r] = vfma(cv, re2[r], sv * pim);
            im2[r] = vfma(cv, im2[r], nsv * pr);
        }
    }

    // ---- lane gates k0..k3 ----
    GATE_LANE2(gc[0], gs[0], xor1_dpp)
    GATE_LANE2(gc[1], gs[1], xor2_dpp)
    GATE_LANE2(gc[2], gs[2], xor4_swz)
    GATE_LANE2(gc[3], gs[3], xor8_swz)

    float acc;
#if HAVE_PLSWAP
    // transpose reg bit 0 (k4) <-> lane bit 4 (k8), per component
#pragma unroll
    for (int r = 0; r < 8; r += 2) {
        float a, bq;
        a = re2[r].x; bq = re2[r + 1].x; pl16_swap(a, bq); re2[r].x = a; re2[r + 1].x = bq;
        a = re2[r].y; bq = re2[r + 1].y; pl16_swap(a, bq); re2[r].y = a; re2[r + 1].y = bq;
        a = im2[r].x; bq = im2[r + 1].x; pl16_swap(a, bq); im2[r].x = a; im2[r + 1].x = bq;
        a = im2[r].y; bq = im2[r + 1].y; pl16_swap(a, bq); im2[r].y = a; im2[r + 1].y = bq;
    }
    GATE_REG2(gc[8], gs[8], 1)          // k8 (now reg bit 0)
    // transpose reg bit 1 (k5) <-> lane bit 5 (k9), per component
#pragma unroll
    for (int r = 0; r < 8; ++r) {
        if (!(r & 2)) {
            const int r2 = r | 2;
            float a, bq;
            a = re2[r].x; bq = re2[r2].x; pl32_swap(a, bq); re2[r].x = a; re2[r2].x = bq;
            a = re2[r].y; bq = re2[r2].y; pl32_swap(a, bq); re2[r].y = a; re2[r2].y = bq;
            a = im2[r].x; bq = im2[r2].x; pl32_swap(a, bq); im2[r].x = a; im2[r2].x = bq;
            a = im2[r].y; bq = im2[r2].y; pl32_swap(a, bq); im2[r].y = a; im2[r2].y = bq;
        }
    }
    GATE_REG2(gc[9], gs[9], 2)          // k9 (now reg bit 1)

    // final Ry through second E: pair (r, r^3) flips k8,k9; sign = reg bit 1
    {
        const v2f cv = splat(c2), sv = splat(2.0f * s2);
        v2f acc2 = splat(0.0f);
#pragma unroll
        for (int r = 0; r < 8; ++r) {
            if (!(r & 2)) {             // k9 = 0 element of the pair
                const int rp = r ^ 3;
                const v2f pa  = vfma(re2[r],  re2[r],  im2[r]  * im2[r]);
                const v2f pb  = vfma(re2[rp], re2[rp], im2[rp] * im2[rp]);
                const v2f dot = vfma(re2[r],  re2[rp], im2[r]  * im2[rp]);
                acc2 = vfma(cv, pb - pa, vfma(sv, dot, acc2));
            }
        }
        acc = acc2.x + acc2.y;
    }
#else
    // fallback: shuffle butterflies for k8,k9 + lane-pair finale
    GATE_LANE2(gc[8], gs[8], [&](float vv) { return __shfl_xor(vv, 16, 64); })
    GATE_LANE2(gc[9], gs[9], [&](float vv) { return __shfl_xor(vv, 32, 64); })
    {
        const float cc = k9 ? c2 : -c2;
        v2f acc2 = splat(0.0f);
#pragma unroll
        for (int r = 0; r < 8; ++r) {
            v2f pr, pim;
            pr.x  = __shfl_xor(re2[r].x, 48, 64);
            pr.y  = __shfl_xor(re2[r].y, 48, 64);
            pim.x = __shfl_xor(im2[r].x, 48, 64);
            pim.y = __shfl_xor(im2[r].y, 48, 64);
            const v2f pown = vfma(re2[r], re2[r], im2[r] * im2[r]);
            const v2f dot  = vfma(re2[r], pr, im2[r] * pim);
            acc2 = vfma(splat(cc), pown, vfma(splat(s2), dot, acc2));
        }
        acc = acc2.x + acc2.y;
    }
#endif

    // ---- wave reduction ----
    acc += xor1_dpp(acc);
    acc += xor2_dpp(acc);
    acc += xor4_swz(acc);
    acc += xor8_swz(acc);
    acc += __shfl_xor(acc, 16, 64);
    acc += __shfl_xor(acc, 32, 64);
    if (lane == 0) out[b] = acc * 0.0009765625f;
}

extern "C" void kernel_launch(void* const* d_in, const int* in_sizes, int n_in,
                              void* d_out, int out_size, void* d_ws, size_t ws_size,
                              hipStream_t stream) {
    const float* inputs = (const float*)d_in[0];   // (8192, 10) float32
    const float* weight = (const float*)d_in[1];   // (23,) float32
    // d_in[2] = entangle_matrix — analytically folded (Gray-code map), unused.
    float* out   = (float*)d_out;                  // (8192,) float32
    int*   flags = (int*)d_ws;                     // 64 ints
    float* gtab  = (float*)d_ws + 64;              // 32 floats

    prep_kernel<<<64, 256, 0, stream>>>(inputs, BATCHN * NQ, weight, flags, gtab);
    qsim_kernel<<<BATCHN / 4, 256, 0, stream>>>(inputs, flags, gtab, out);
}